// Round 8
// baseline (242.072 us; speedup 1.0000x reference)
//
#include <hip/hip_runtime.h>
#include <stdint.h>

// Ternary CNN, 7 layers, all-NHWC pipeline.
// L0: fp64-exact conv+pool+sign -> NHWC4. L1/L2: dot4 channel-packed convs.
// L3-L6: implicit-GEMM int8 MFMA, prepacked A-fragments, LDS-staged rows.
// Round 8: 512-thread MFMA blocks. CGW=2 puts both cout-halves of a pixel in
// ONE block (r7's grid.x=2 split wrote 32B half-lines from different XCDs ->
// partial-sector HBM writes). L3 moves to 8 rows/block (read amp 1.5->1.25).
//
// Workspace:
//  A  @ 0        : L0 out NHWC4 4.1MB ; L2 out NHWC16 15.5MB ; L4 out NHWC64 58.0MB
//  B  @ 58491136 : L1 out NHWC8 8.0MB ; L3 out NHWC32 30.0MB ; L5 out NHWC32 28.1MB
//  pA @ 88475904 : packed sign A-fragments, 50176 B (L3@0, L4@6144, L5@26624, L6@45056)

#define DEVINL __device__ __forceinline__
typedef int i32x4 __attribute__((ext_vector_type(4)));

DEVINL int dot4(uint32_t a, uint32_t b, int c) {
#if __has_builtin(__builtin_amdgcn_sdot4)
    return __builtin_amdgcn_sdot4((int)a, (int)b, c, false);
#else
    #pragma unroll
    for (int i = 0; i < 4; ++i)
        c += (int)(int8_t)(a >> (8 * i)) * (int)(int8_t)(b >> (8 * i));
    return c;
#endif
}

DEVINL uint32_t clampb(int v) {           // clamp to [-1,1], return low byte
    v = v > 1 ? 1 : (v < -1 ? -1 : v);
    return (uint32_t)(uint8_t)(int8_t)v;
}

// ---------------- Layer 0: conv(raw fp32, sign(w)) -> maxpool2 -> sign -> NHWC4
__global__ __launch_bounds__(256) void conv0_pool_sign(
    const float* __restrict__ x, const float* __restrict__ w,
    uint32_t* __restrict__ out)
{
    __shared__ float ws[108];
    const int t = threadIdx.x;
    if (t < 108) {
        float v = w[t];
        ws[t] = (v > 0.f) ? 1.f : ((v < 0.f) ? -1.f : 0.f);
    }
    __syncthreads();
    const int idx = blockIdx.x * 256 + t;
    if (idx >= 64 * 127 * 127) return;
    const int px = idx % 127;
    const int py = (idx / 127) % 127;
    const int n  = idx / (127 * 127);

    double acc[4][4];   // [co][pos]
    #pragma unroll
    for (int co = 0; co < 4; ++co)
        #pragma unroll
        for (int p = 0; p < 4; ++p) acc[co][p] = 0.0;

    for (int ci = 0; ci < 3; ++ci) {
        float patch[4][4];
        const float* xp = x + (((size_t)n * 3 + ci) * 256 + 2 * py) * 256 + 2 * px;
        #pragma unroll
        for (int r = 0; r < 4; ++r) {
            const float2* q = (const float2*)(xp + r * 256);
            float2 p01 = q[0], p23 = q[1];
            patch[r][0] = p01.x; patch[r][1] = p01.y;
            patch[r][2] = p23.x; patch[r][3] = p23.y;
        }
        #pragma unroll
        for (int co = 0; co < 4; ++co) {
            const float* wsc = &ws[co * 27 + ci * 9];
            #pragma unroll
            for (int ky = 0; ky < 3; ++ky)
                #pragma unroll
                for (int kx = 0; kx < 3; ++kx) {
                    const double wv = (double)wsc[ky * 3 + kx];
                    acc[co][0] += (double)patch[ky][kx]         * wv;
                    acc[co][1] += (double)patch[ky][kx + 1]     * wv;
                    acc[co][2] += (double)patch[ky + 1][kx]     * wv;
                    acc[co][3] += (double)patch[ky + 1][kx + 1] * wv;
                }
        }
    }
    uint32_t u = 0;
    #pragma unroll
    for (int co = 0; co < 4; ++co) {
        const double m = fmax(fmax(acc[co][0], acc[co][1]), fmax(acc[co][2], acc[co][3]));
        const uint32_t s = (m > 0.0) ? 1u : ((m < 0.0) ? 0xFFu : 0u);
        u |= s << (8 * co);
    }
    out[idx] = u;
}

// ---------------- L1: NHWC4 (127x127) -> NHWC8 (125x125)
__global__ __launch_bounds__(256) void conv_l1(
    const uint32_t* __restrict__ in, const float* __restrict__ w,
    uint2* __restrict__ out)
{
    __shared__ uint32_t pw[72];
    const int t = threadIdx.x;
    if (t < 72) {
        const int co = t / 9, tap = t % 9;
        uint32_t u = 0;
        #pragma unroll
        for (int ci = 0; ci < 4; ++ci) {
            float v = w[(co * 4 + ci) * 9 + tap];
            uint32_t s = (v > 0.f) ? 1u : ((v < 0.f) ? 0xFFu : 0u);
            u |= s << (8 * ci);
        }
        pw[t] = u;
    }
    __syncthreads();

    const int idx = blockIdx.x * 256 + t;   // 64*125*32 = 256000 exact
    const int xg  = idx & 31;
    const int rest = idx >> 5;
    const int py  = rest % 125;
    const int n   = rest / 125;
    int px0 = xg * 4; if (px0 > 121) px0 = 121;

    const uint32_t* base = in + ((size_t)(n * 127 + py) * 127 + px0);
    uint32_t d[3][6];
    #pragma unroll
    for (int r = 0; r < 3; ++r)
        #pragma unroll
        for (int c = 0; c < 6; ++c)
            d[r][c] = base[r * 127 + c];

    int acc[4][8];
    #pragma unroll
    for (int j = 0; j < 4; ++j)
        #pragma unroll
        for (int co = 0; co < 8; ++co) acc[j][co] = 0;

    #pragma unroll
    for (int ky = 0; ky < 3; ++ky)
        #pragma unroll
        for (int kx = 0; kx < 3; ++kx) {
            const int tap = ky * 3 + kx;
            #pragma unroll
            for (int co = 0; co < 8; ++co) {
                const uint32_t wv = pw[co * 9 + tap];
                #pragma unroll
                for (int j = 0; j < 4; ++j)
                    acc[j][co] = dot4(d[ky][j + kx], wv, acc[j][co]);
            }
        }

    uint2* orow = out + ((size_t)(n * 125 + py) * 125 + px0);
    #pragma unroll
    for (int j = 0; j < 4; ++j) {
        uint32_t u0 = 0, u1 = 0;
        #pragma unroll
        for (int co = 0; co < 4; ++co) u0 |= clampb(acc[j][co]) << (8 * co);
        #pragma unroll
        for (int co = 0; co < 4; ++co) u1 |= clampb(acc[j][co + 4]) << (8 * co);
        orow[j] = make_uint2(u0, u1);
    }
}

// ---------------- L2: NHWC8 (125x125) -> NHWC16 (123x123)
__global__ __launch_bounds__(256) void conv_l2(
    const uint32_t* __restrict__ in, const float* __restrict__ w,
    i32x4* __restrict__ out)
{
    __shared__ uint32_t pw[288];
    const int t = threadIdx.x;
    for (int i = t; i < 288; i += 256) {
        const int co = i / 18, r = i % 18, tap = r / 2, half = r % 2;
        uint32_t u = 0;
        #pragma unroll
        for (int ci = 0; ci < 4; ++ci) {
            float v = w[(co * 8 + half * 4 + ci) * 9 + tap];
            uint32_t s = (v > 0.f) ? 1u : ((v < 0.f) ? 0xFFu : 0u);
            u |= s << (8 * ci);
        }
        pw[i] = u;
    }
    __syncthreads();

    const int idx = blockIdx.x * 256 + t;
    if (idx >= 64 * 123 * 31) return;
    const int xg   = idx % 31;
    const int rest = idx / 31;
    const int py   = rest % 123;
    const int n    = rest / 123;
    int px0 = xg * 4; if (px0 > 119) px0 = 119;

    const uint32_t* base = in + ((size_t)(n * 125 + py) * 125 + px0) * 2;
    uint32_t d[3][6][2];
    #pragma unroll
    for (int r = 0; r < 3; ++r)
        #pragma unroll
        for (int c = 0; c < 6; ++c) {
            d[r][c][0] = base[(r * 125 + c) * 2];
            d[r][c][1] = base[(r * 125 + c) * 2 + 1];
        }

    int acc[4][16];
    #pragma unroll
    for (int j = 0; j < 4; ++j)
        #pragma unroll
        for (int co = 0; co < 16; ++co) acc[j][co] = 0;

    #pragma unroll
    for (int ky = 0; ky < 3; ++ky)
        #pragma unroll
        for (int kx = 0; kx < 3; ++kx) {
            const int tap = ky * 3 + kx;
            #pragma unroll
            for (int co = 0; co < 16; ++co) {
                const uint32_t w0 = pw[(co * 9 + tap) * 2];
                const uint32_t w1 = pw[(co * 9 + tap) * 2 + 1];
                #pragma unroll
                for (int j = 0; j < 4; ++j)
                    acc[j][co] = dot4(d[ky][j + kx][1], w1,
                                 dot4(d[ky][j + kx][0], w0, acc[j][co]));
            }
        }

    i32x4* orow = out + ((size_t)(n * 123 + py) * 123 + px0);
    #pragma unroll
    for (int j = 0; j < 4; ++j) {
        uint32_t u[4];
        #pragma unroll
        for (int q = 0; q < 4; ++q) {
            u[q] = 0;
            #pragma unroll
            for (int b = 0; b < 4; ++b)
                u[q] |= clampb(acc[j][q * 4 + b]) << (8 * b);
        }
        orow[j] = (i32x4){(int)u[0], (int)u[1], (int)u[2], (int)u[3]};
    }
}

// ---------------- Prepack sign A-fragments for L3..L6 (runs once, 50176 B).
// Layout: per layer, cg-major then mt, f, lane, j. The conv kernels index it
// as cgw*(MTILES*NMF*1024): for L5 (new MTILES=1, CGW=2) this lands exactly on
// the old mt=0/mt=1 blocks, so the packing is unchanged.
__global__ __launch_bounds__(256) void prepack_w(
    const float* __restrict__ w3, const float* __restrict__ w4,
    const float* __restrict__ w5, const float* __restrict__ w6,
    int8_t* __restrict__ pA)
{
    const int idx = blockIdx.x * 256 + threadIdx.x;
    const float* w; int CIN, COUT, MTILES, NMF, off;
    if      (idx < 6144)  { w = w3; CIN = 16; COUT = 32; MTILES = 2; NMF = 3; off = 0; }
    else if (idx < 26624) { w = w4; CIN = 32; COUT = 64; MTILES = 2; NMF = 5; off = 6144; }
    else if (idx < 45056) { w = w5; CIN = 64; COUT = 32; MTILES = 2; NMF = 9; off = 26624; }
    else if (idx < 50176) { w = w6; CIN = 32; COUT = 2;  MTILES = 1; NMF = 5; off = 45056; }
    else return;
    const int TP = 64 / CIN;
    const int s   = idx - off;
    const int per = MTILES * NMF * 1024;
    const int cg  = s / per;
    const int rem = s % per;
    const int mt  = rem / (NMF * 1024);
    const int r2  = rem % (NMF * 1024);
    const int f   = r2 >> 10;
    const int l   = (r2 >> 4) & 63;
    const int j   = r2 & 15;
    const int m   = l & 15;
    const int g   = l >> 4;
    const int k   = g * 16 + j;
    const int tap = f * TP + k / CIN;
    const int ci  = k % CIN;
    const int co  = cg * (16 * MTILES) + mt * 16 + m;
    int8_t v = 0;
    if (tap < 9 && co < COUT) {
        float x = w[((size_t)co * CIN + ci) * 9 + tap];
        v = (x > 0.f) ? (int8_t)1 : ((x < 0.f) ? (int8_t)(-1) : (int8_t)0);
    }
    pA[idx] = v;
}

// ---------------- L3..L6: implicit-GEMM MFMA conv, NHWC int8, prepacked A.
// Block = 64*R*CGW threads. R = output rows per block; CGW cout-halves live in
// the SAME block (full pixel records written from one CU -> full-line HBM
// writes). Stage R+2 rows x 66 cols as NP planes of 16B records, one barrier,
// 4 fragments of ds_read_b128 + MFMA per wave.
template <int CIN, int COUT, int MTILES, int CGW, int R, int WI, bool FOUT>
__global__ __launch_bounds__(64 * R * CGW) void conv_mfma(
    const int8_t* __restrict__ in, const int8_t* __restrict__ packA,
    void* __restrict__ outp, int Wo)
{
    constexpr int TP  = 64 / CIN;
    constexpr int NMF = (9 + TP - 1) / TP;
    constexpr int NP  = CIN / 16;
    constexpr int CB  = 66;
    constexpr int NT  = 64 * R * CGW;
    constexpr int SR  = R + 2;
    constexpr int NU  = (SR * CB + NT - 1) / NT;
    __shared__ __align__(16) int8_t lds[NP * SR * CB * 16];

    const int t  = threadIdx.x;
    const int n  = blockIdx.z;
    const int by = blockIdx.y >> 1;
    const int bx = blockIdx.y & 1;
    const int y0 = by * R;
    const int f0 = bx * 4;
    const int cbase = f0 * 16;
    const int ncols = (WI - cbase < CB) ? (WI - cbase) : CB;
    const int npx   = SR * ncols;

    // ---- issue staging loads: pixel-major, full CIN-byte records
    const int8_t* nin = in + (size_t)n * WI * WI * CIN;
    i32x4 st[NU][NP];
    #pragma unroll
    for (int u = 0; u < NU; ++u) {
        int p  = t + u * NT;
        int pp = p < npx ? p : npx - 1;
        int row  = pp / ncols;
        int col  = cbase + pp % ncols;
        int grow = y0 + row; if (grow > WI - 1) grow = WI - 1;
        const int8_t* src = nin + ((size_t)grow * WI + col) * CIN;
        #pragma unroll
        for (int pl = 0; pl < NP; ++pl)
            st[u][pl] = *(const i32x4*)(src + pl * 16);
    }

    // ---- A fragments from prepacked global (coalesced, L2-hot)
    const int l = t & 63, wv = t >> 6, g = l >> 4, npix = l & 15;
    const int cgw  = (CGW == 2 && wv >= R) ? 1 : 0;
    const int wrow = wv - cgw * R;
    i32x4 a[MTILES][NMF];
    {
        const int8_t* ap = packA + (size_t)cgw * MTILES * NMF * 1024 + l * 16;
        #pragma unroll
        for (int mt = 0; mt < MTILES; ++mt)
            #pragma unroll
            for (int f = 0; f < NMF; ++f)
                a[mt][f] = *(const i32x4*)(ap + (mt * NMF + f) * 1024);
    }

    // ---- write staged pixels to LDS planes
    #pragma unroll
    for (int u = 0; u < NU; ++u) {
        int p = t + u * NT;
        if (p < npx) {
            int row = p / ncols, colrel = p % ncols;
            #pragma unroll
            for (int pl = 0; pl < NP; ++pl)
                *(i32x4*)&lds[(size_t)(pl * SR * CB + row * CB + colrel) * 16] = st[u][pl];
        }
    }
    __syncthreads();

    const int y = y0 + wrow;
    if (y >= Wo) return;

    // per-lane LDS offsets per fragment-MFMA
    const int gdiv  = (g * 16) / CIN;
    const int plane = ((g * 16) % CIN) / 16;
    int loff[NMF];
    #pragma unroll
    for (int f = 0; f < NMF; ++f) {
        int tap = f * TP + gdiv;
        if (tap > 8) tap = 8;               // A is zero there; any valid addr
        loff[f] = (plane * SR * CB + (wrow + tap / 3) * CB + (tap % 3) + npix) << 4;
    }

    #pragma unroll
    for (int i = 0; i < 4; ++i) {
        int x0 = (f0 + i) * 16;
        if (x0 > Wo - 16) x0 = Wo - 16;
        const int xrel = x0 - cbase;

        i32x4 bv[NMF];
        #pragma unroll
        for (int f = 0; f < NMF; ++f)
            bv[f] = *(const i32x4*)&lds[loff[f] + (xrel << 4)];

        i32x4 acc[MTILES];
        #pragma unroll
        for (int mt = 0; mt < MTILES; ++mt) {
            acc[mt] = (i32x4){0, 0, 0, 0};
            #pragma unroll
            for (int f = 0; f < NMF; ++f)
                acc[mt] = __builtin_amdgcn_mfma_i32_16x16x64_i8(a[mt][f], bv[f], acc[mt], 0, 0, 0);
        }

        if (!FOUT) {
            uint8_t* orow = (uint8_t*)outp + ((size_t)n * Wo + y) * (size_t)Wo * COUT
                          + (size_t)(x0 + npix) * COUT
                          + cgw * (16 * MTILES) + (g << 2);
            #pragma unroll
            for (int mt = 0; mt < MTILES; ++mt) {
                uint32_t u = 0;
                #pragma unroll
                for (int rr = 0; rr < 4; ++rr)
                    u |= clampb(acc[mt][rr]) << (8 * rr);
                *(uint32_t*)(orow + mt * 16) = u;
            }
        } else {
            float* fo = (float*)outp;
            #pragma unroll
            for (int rr = 0; rr < 4; ++rr) {
                const int m = g * 4 + rr;
                if (m < COUT) {
                    int v = acc[0][rr];
                    v = v > 1 ? 1 : (v < -1 ? -1 : v);
                    fo[((size_t)(n * COUT + m) * Wo + y) * Wo + x0 + npix] = (float)v;
                }
            }
        }
    }
}

extern "C" void kernel_launch(void* const* d_in, const int* in_sizes, int n_in,
                              void* d_out, int out_size, void* d_ws, size_t ws_size,
                              hipStream_t stream) {
    const float* x  = (const float*)d_in[0];
    const float* w0 = (const float*)d_in[1];
    const float* w1 = (const float*)d_in[2];
    const float* w2 = (const float*)d_in[3];
    const float* w3 = (const float*)d_in[4];
    const float* w4 = (const float*)d_in[5];
    const float* w5 = (const float*)d_in[6];
    const float* w6 = (const float*)d_in[7];

    int8_t* A  = (int8_t*)d_ws;
    int8_t* B  = A + 58491136;
    int8_t* pA = B + 29984768;

    prepack_w<<<196, 256, 0, stream>>>(w3, w4, w5, w6, pA);

    // L0: (64,3,256,256) fp32 -> NHWC4 (64,127,127,4)
    conv0_pool_sign<<<4033, 256, 0, stream>>>(x, w0, (uint32_t*)A);
    // L1: NHWC4 -> NHWC8 (64,125,125,8)
    conv_l1<<<1000, 256, 0, stream>>>((const uint32_t*)A, w1, (uint2*)B);
    // L2: NHWC8 -> NHWC16 (64,123,123,16)
    conv_l2<<<954, 256, 0, stream>>>((const uint32_t*)B, w2, (i32x4*)A);

    // L3: 16->32, 123 -> 121.  R=8, CGW=1, MTILES=2. 512 thr, 10.6KB LDS.
    conv_mfma<16, 32, 2, 1, 8, 123, false><<<dim3(1, 16 * 2, 64), 512, 0, stream>>>(A, pA + 0, B, 121);
    // L4: 32->64, 121 -> 119.  R=4, CGW=2, MTILES=2. 512 thr, 12.7KB LDS.
    conv_mfma<32, 64, 2, 2, 4, 121, false><<<dim3(1, 30 * 2, 64), 512, 0, stream>>>(B, pA + 6144, A, 119);
    // L5: 64->32, 119 -> 117.  R=4, CGW=2, MTILES=1. 512 thr, 25.3KB LDS.
    conv_mfma<64, 32, 1, 2, 4, 119, false><<<dim3(1, 30 * 2, 64), 512, 0, stream>>>(A, pA + 26624, B, 117);
    // L6: 32->2, 117 -> 115, float NCHW out.  R=4, CGW=1, MTILES=1. 256 thr.
    conv_mfma<32, 2, 1, 1, 4, 117, true ><<<dim3(1, 29 * 2, 64), 256, 0, stream>>>(B, pA + 45056, d_out, 115);
}